// Round 13
// baseline (164.960 us; speedup 1.0000x reference)
//
#include <hip/hip_runtime.h>

// ---------------------------------------------------------------------------
// MinConv2dLSTM: 2x (3x3 conv -> minLSTM gates -> scan over S)
// B=4 S=16 H=W=32, layer0: Cin=32, layer1: Cin=64, gates Cout=256 (4x64)
// R12 resubmit: barrier-free conv tap loop. A-patch in LDS (staged once, 1
//      barrier); weights stream global->VGPR (coalesced co-major layout),
//      3-buffer, 2 taps ahead. No lsB, no per-tap barriers, half LDS traffic.
// ---------------------------------------------------------------------------

typedef __bf16 bf16x8 __attribute__((ext_vector_type(8)));
typedef __bf16 bf16x4 __attribute__((ext_vector_type(4)));
typedef float f32x4 __attribute__((ext_vector_type(4)));

#define N_IMG 64      // B*S
#define HP 34         // padded H/W
#define COUT 256

__device__ __forceinline__ float sigf(float x) { return 1.0f / (1.0f + __expf(-x)); }

// ---------------------------------------------------------------------------
// pack_x: x (64,32,32,32) NCHW fp32 -> xT padded NHWC bf16 (64,34,34,32)
// ---------------------------------------------------------------------------
__global__ __launch_bounds__(256) void pack_x_k(const float* __restrict__ x,
                                                __bf16* __restrict__ xT) {
  __shared__ float ls[32][33];
  const int n = blockIdx.x >> 5;
  const int h = blockIdx.x & 31;
  const int t = threadIdx.x;
  {
    const int w = t & 31, g4 = t >> 5;
    const float* src = x + (((size_t)n * 32) << 10) + (h << 5);
#pragma unroll
    for (int j = 0; j < 4; ++j) {
      int ci = g4 * 4 + j;
      ls[ci][w] = src[((size_t)ci << 10) + w];
    }
  }
  __syncthreads();
  {
    const int ci = t & 31, w4 = t >> 5;
    __bf16* dst = xT + ((size_t)(n * HP + h + 1) * HP + 1) * 32 + ci;
#pragma unroll
    for (int j = 0; j < 4; ++j) {
      int w = w4 * 4 + j;
      dst[w * 32] = (__bf16)ls[ci][w];
    }
  }
}

// ---------------------------------------------------------------------------
// pack_w: w (256,CIN,3,3) fp32 -> wT3 [tap][chunk][co][8ci] bf16
// (co-major within a chunk-plane: 16-lane fragment loads are contiguous)
// ---------------------------------------------------------------------------
template <int CIN>
__global__ __launch_bounds__(256) void pack_w_k(const float* __restrict__ w,
                                                __bf16* __restrict__ wT3) {
  constexpr int CHUNKS = CIN / 8;
  int g = blockIdx.x * 256 + threadIdx.x;
  if (g >= 256 * 9 * CIN) return;
  const int j = g & 7;             // ci within chunk
  const int co = (g >> 3) & 255;
  const int r = g >> 11;           // t*CHUNKS + ca
  const int ca = r % CHUNKS;
  const int t = r / CHUNKS;
  const int ci = ca * 8 + j;
  wT3[g] = (__bf16)w[(size_t)(co * CIN + ci) * 9 + t];
}

// ---------------------------------------------------------------------------
// conv_gemm: implicit-GEMM 3x3 conv, bf16 MFMA 16x16x32.
// Block: 256 thr = 4 waves, tile 128(m=pixels: 4 image rows) x 128(n=cout).
// lsA: chunk-major [CHUNKS][6*34] bf16x8 — staged ONCE; all 9 taps read at
//      tap-constant offsets (<=2-way conflicts). ONE barrier total.
// Weights: global->VGPR bf16x8 fragments, [t%3] triple buffer, issued 2 taps
//      ahead; compiler-tracked vmcnt. No lsB, no per-tap barriers.
// ---------------------------------------------------------------------------
template <int CIN, bool LAYER1>
__global__ __launch_bounds__(256, 2) void conv_gemm_k(
    const __bf16* __restrict__ xT,   // padded NHWC (64,34,34,CIN)
    const __bf16* __restrict__ wT3,  // [9][CHUNKS][256][8]
    const float* __restrict__ bias,  // [256]
    __bf16* __restrict__ gates) {
  constexpr int NKK = CIN / 32;     // MFMA k-groups per tap
  constexpr int CHUNKS = CIN / 8;   // 16B ci-chunks per pixel
  constexpr int PLANE = 204;        // 6*34 pixel slots per chunk-plane
  __shared__ bf16x8 lsA[CHUNKS * PLANE];

  const int tid = threadIdx.x;
  const int lane = tid & 63;
  const int wid = tid >> 6;
  const int wr = wid >> 1, wc = wid & 1;
  const int g = lane >> 4;          // ci-chunk group
  const int li = lane & 15;         // m / co within fragment

  const int bx = blockIdx.x;        // m-block: 8 per image
  const int by = blockIdx.y;        // co-block (2)
  const int n = bx >> 3;
  const int h0 = (bx & 7) << 2;     // first padded row of the 4 image rows
  const int co0 = by << 7;

  f32x4 acc[4][4] = {};

  // --- stage A once: padded rows h0..h0+5, cols 0..33, all ci (chunk-major)
  for (int gi = tid; gi < CHUNKS * PLANE; gi += 256) {
    const int ch = gi & (CHUNKS - 1);
    const int pos = gi / CHUNKS;          // r*34 + w
    const int r = pos / 34;
    const int w = pos - r * 34;
    lsA[ch * PLANE + pos] = *reinterpret_cast<const bf16x8*>(
        xT + ((size_t)(n * HP + h0 + r) * HP + w) * CIN + ch * 8);
  }

  // per-(mi) pixel slot within the A patch (tap-invariant)
  int posm[4];
#pragma unroll
  for (int mi = 0; mi < 4; ++mi) {
    const int m = wr * 64 + mi * 16 + li;
    posm[mi] = (m >> 5) * 34 + (m & 31);
  }

  // weight fragment pointer: frag (t, ca, ni) at [(t*CHUNKS+ca)*256 + co]
  const bf16x8* wp = reinterpret_cast<const bf16x8*>(wT3);
  const int cobase = co0 + wc * 64 + li;

  bf16x8 wreg[3][NKK][4];
  auto loadW = [&](int buf, int t) {
#pragma unroll
    for (int kk = 0; kk < NKK; ++kk)
#pragma unroll
      for (int ni = 0; ni < 4; ++ni)
        wreg[buf][kk][ni] =
            wp[(size_t)(t * CHUNKS + kk * 4 + g) * 256 + cobase + ni * 16];
  };

  loadW(0, 0);
  loadW(1, 1);
  __syncthreads();          // lsA ready (also covers weight reg deps via cnt)

#pragma unroll
  for (int t = 0; t < 9; ++t) {
    if (t < 7) loadW((t + 2) % 3, t + 2);
    const int kh = t / 3;
    const int kw = t - kh * 3;
    const int tapoff = kh * 34 + kw;
    const int buf = t % 3;
#pragma unroll
    for (int kk = 0; kk < NKK; ++kk) {
      const int ca = kk * 4 + g;
      bf16x8 af[4];
#pragma unroll
      for (int mi = 0; mi < 4; ++mi)
        af[mi] = lsA[ca * PLANE + posm[mi] + tapoff];
#pragma unroll
      for (int mi = 0; mi < 4; ++mi)
#pragma unroll
        for (int ni = 0; ni < 4; ++ni) {
          if constexpr (!LAYER1)
            acc[mi][ni] = __builtin_amdgcn_mfma_f32_16x16x32_bf16(
                af[mi], wreg[buf][kk][ni], acc[mi][ni], 0, 0, 0);
          else
            acc[mi][ni] = __builtin_amdgcn_mfma_f32_16x16x32_bf16(
                wreg[buf][kk][ni], af[mi], acc[mi][ni], 0, 0, 0);
        }
    }
  }

  // epilogue: C/D map col=lane&15, row=(lane>>4)*4+r
#pragma unroll
  for (int mi = 0; mi < 4; ++mi)
#pragma unroll
    for (int ni = 0; ni < 4; ++ni)
#pragma unroll
      for (int r = 0; r < 4; ++r) {
        if constexpr (!LAYER1) {
          const int m_loc = wr * 64 + mi * 16 + (g << 2) + r;
          const int co = co0 + wc * 64 + ni * 16 + li;
          const size_t m = (size_t)bx * 128 + m_loc;
          gates[m * 256 + co] = (__bf16)(acc[mi][ni][r] + bias[co]);
        } else {
          const int co = co0 + wc * 64 + ni * 16 + (g << 2) + r;
          const int m_loc = wr * 64 + mi * 16 + li;
          const int m = bx * 128 + m_loc;
          const int nimg = m >> 10, p = m & 1023;
          gates[((size_t)nimg * 256 + co) * 1024 + p] =
              (__bf16)(acc[mi][ni][r] + bias[co]);
        }
      }
}

// ---------------------------------------------------------------------------
// scan0: gates [m][256] bf16 -> h0T padded NHWC bf16 (64,34,34,64)
// thread = (b, p, c-quad): bf16x4 loads/stores (8B/lane). 256 blocks x 256.
// ---------------------------------------------------------------------------
__global__ __launch_bounds__(256) void scan0_k(const __bf16* __restrict__ gates,
                                               __bf16* __restrict__ h0T) {
  const int g = blockIdx.x * 256 + threadIdx.x;  // 4*1024*16
  const int c = (g & 15) * 4;
  const int p = (g >> 4) & 1023;
  const int b = g >> 14;
  const int h = p >> 5, w = p & 31;
  float cst[4] = {0.5f, 0.5f, 0.5f, 0.5f};
#pragma unroll 4
  for (int s = 0; s < 16; ++s) {
    const size_t base = ((size_t)((b * 16 + s) * 1024 + p)) * 256 + c;
    const bf16x4* gp = reinterpret_cast<const bf16x4*>(gates + base);
    const bf16x4 ig4 = gp[0], fg4 = gp[16], og4 = gp[32], cd4 = gp[48];
    bf16x4 hv4;
#pragma unroll
    for (int j = 0; j < 4; ++j) {
      const float it = sigf((float)ig4[j]), ft = sigf((float)fg4[j]);
      const float inv = 1.0f / (it + ft);
      const float cd_ = (float)cd4[j];
      const float gc = (cd_ >= 0.0f) ? (cd_ + 0.5f) : sigf(cd_);
      cst[j] = (ft * inv) * cst[j] + (it * inv) * gc;
      hv4[j] = (__bf16)(sigf((float)og4[j]) * cst[j]);
    }
    *reinterpret_cast<bf16x4*>(
        h0T + ((size_t)((b * 16 + s) * HP + h + 1) * HP + (w + 1)) * 64 + c) = hv4;
  }
}

// ---------------------------------------------------------------------------
// scan1: gates [n][256][1024] bf16 -> out fp32 (B,S,64,32,32)
// thread = (b, c, 4 pixels): bf16x4 loads (8B), float4 stores. 256 blocks.
// ---------------------------------------------------------------------------
__global__ __launch_bounds__(256) void scan1_k(const __bf16* __restrict__ gates,
                                               float* __restrict__ out) {
  const int g = blockIdx.x * 256 + threadIdx.x;  // 4*64*256
  const int p0 = (g & 255) * 4;
  const int c = (g >> 8) & 63;
  const int b = g >> 14;
  float cst[4] = {0.5f, 0.5f, 0.5f, 0.5f};
#pragma unroll 2
  for (int s = 0; s < 16; ++s) {
    const size_t base = ((size_t)(b * 16 + s) * 256 + c) * 1024 + p0;
    const bf16x4 ig4 = *reinterpret_cast<const bf16x4*>(gates + base);
    const bf16x4 fg4 = *reinterpret_cast<const bf16x4*>(gates + base + 64 * 1024);
    const bf16x4 og4 = *reinterpret_cast<const bf16x4*>(gates + base + 128 * 1024);
    const bf16x4 cd4 = *reinterpret_cast<const bf16x4*>(gates + base + 192 * 1024);
    f32x4 hv;
#pragma unroll
    for (int j = 0; j < 4; ++j) {
      const float it = sigf((float)ig4[j]), ft = sigf((float)fg4[j]);
      const float inv = 1.0f / (it + ft);
      const float cd_ = (float)cd4[j];
      const float gc = (cd_ >= 0.0f) ? (cd_ + 0.5f) : sigf(cd_);
      cst[j] = (ft * inv) * cst[j] + (it * inv) * gc;
      hv[j] = sigf((float)og4[j]) * cst[j];
    }
    *reinterpret_cast<f32x4*>(
        out + ((size_t)((b * 16 + s) * 64 + c)) * 1024 + p0) = hv;
  }
}

// ---------------------------------------------------------------------------
extern "C" void kernel_launch(void* const* d_in, const int* in_sizes, int n_in,
                              void* d_out, int out_size, void* d_ws,
                              size_t ws_size, hipStream_t stream) {
  const float* x = (const float*)d_in[0];   // (4,16,32,32,32)
  const float* w0 = (const float*)d_in[1];  // (256,32,3,3)
  const float* b0 = (const float*)d_in[2];  // (256)
  const float* w1 = (const float*)d_in[3];  // (256,64,3,3)
  const float* b1 = (const float*)d_in[4];  // (256)
  float* out = (float*)d_out;               // (4,16,64,32,32)

  char* ws = (char*)d_ws;
  const size_t XT_BYTES = (size_t)N_IMG * HP * HP * 32 * 2;
  const size_t H0_BYTES = (size_t)N_IMG * HP * HP * 64 * 2;
  const size_t W0T_BYTES = (size_t)256 * 9 * 32 * 2;
  const size_t W1T_BYTES = (size_t)256 * 9 * 64 * 2;
  __bf16* xT = (__bf16*)ws;
  __bf16* h0T = (__bf16*)(ws + XT_BYTES);
  __bf16* w0T = (__bf16*)(ws + XT_BYTES + H0_BYTES);
  __bf16* w1T = (__bf16*)(ws + XT_BYTES + H0_BYTES + W0T_BYTES);
  __bf16* gates = (__bf16*)(ws + XT_BYTES + H0_BYTES + W0T_BYTES + W1T_BYTES);
  (void)ws_size; (void)n_in; (void)in_sizes; (void)out_size;

  hipMemsetAsync(xT, 0, XT_BYTES, stream);
  hipMemsetAsync(h0T, 0, H0_BYTES, stream);

  pack_x_k<<<N_IMG * 32, 256, 0, stream>>>(x, xT);
  pack_w_k<32><<<(256 * 9 * 32 + 255) / 256, 256, 0, stream>>>(w0, w0T);
  pack_w_k<64><<<(256 * 9 * 64 + 255) / 256, 256, 0, stream>>>(w1, w1T);

  // layer 0
  conv_gemm_k<32, false><<<dim3(512, 2), 256, 0, stream>>>(xT, w0T, b0, gates);
  scan0_k<<<256, 256, 0, stream>>>(gates, h0T);
  // layer 1
  conv_gemm_k<64, true><<<dim3(512, 2), 256, 0, stream>>>(h0T, w1T, b1, gates);
  scan1_k<<<256, 256, 0, stream>>>(gates, out);
}

// Round 15
// 157.691 us; speedup vs baseline: 1.0461x; 1.0461x over previous
//
#include <hip/hip_runtime.h>

// ---------------------------------------------------------------------------
// MinConv2dLSTM: 2x (3x3 conv -> minLSTM gates -> scan over S)
// B=4 S=16 H=W=32, layer0: Cin=32, layer1: Cin=64, gates Cout=256 (4x64)
// R14 resubmit: dispatch-count reduction 9 -> 5 nodes. prep_k fuses pack_x +
//      both weight packs + halo zeroing (replaces both memsets). Convs (R12
//      barrier-free reg-weight) and scans byte-identical to R13.
// ---------------------------------------------------------------------------

typedef __bf16 bf16x8 __attribute__((ext_vector_type(8)));
typedef __bf16 bf16x4 __attribute__((ext_vector_type(4)));
typedef float f32x4 __attribute__((ext_vector_type(4)));

#define N_IMG 64      // B*S
#define HP 34         // padded H/W
#define COUT 256

__device__ __forceinline__ float sigf(float x) { return 1.0f / (1.0f + __expf(-x)); }

// ---------------------------------------------------------------------------
// prep_k: ONE kernel for all preprocessing.
//  blocks [0,2048):   pack_x  — x NCHW fp32 -> xT padded NHWC bf16 (interior)
//  blocks [2048,2560): grid-stride elementwise jobs:
//    job0: zero xT halo   (64 img x 132 halo px x 32c, bf16x4 units)
//    job1: zero h0T halo  (64 img x 132 halo px x 64c, bf16x4 units)
//    job2: pack w0 -> w0T3 [tap][chunk][co][8ci]
//    job3: pack w1 -> w1T3 [tap][chunk][co][8ci]
// ---------------------------------------------------------------------------
__global__ __launch_bounds__(256) void prep_k(
    const float* __restrict__ x, const float* __restrict__ w0,
    const float* __restrict__ w1, __bf16* __restrict__ xT,
    __bf16* __restrict__ h0T, __bf16* __restrict__ w0T3,
    __bf16* __restrict__ w1T3) {
  const int bid = blockIdx.x;
  if (bid < 2048) {
    // ---- pack_x: one block per (n, h) ----
    __shared__ float ls[32][33];
    const int n = bid >> 5;
    const int h = bid & 31;
    const int t = threadIdx.x;
    {
      const int w = t & 31, g4 = t >> 5;
      const float* src = x + (((size_t)n * 32) << 10) + (h << 5);
#pragma unroll
      for (int j = 0; j < 4; ++j) {
        int ci = g4 * 4 + j;
        ls[ci][w] = src[((size_t)ci << 10) + w];
      }
    }
    __syncthreads();
    {
      const int ci = t & 31, w4 = t >> 5;
      __bf16* dst = xT + ((size_t)(n * HP + h + 1) * HP + 1) * 32 + ci;
#pragma unroll
      for (int j = 0; j < 4; ++j) {
        int w = w4 * 4 + j;
        dst[w * 32] = (__bf16)ls[ci][w];
      }
    }
    return;
  }
  // ---- elementwise jobs, grid-stride over 512 blocks ----
  constexpr int NT = 512 * 256;
  constexpr int J0 = 64 * 132 * 8;    // 67584  xT-halo bf16x4 units
  constexpr int J1 = 64 * 132 * 16;   // 135168 h0T-halo bf16x4 units
  constexpr int J2 = 256 * 9 * 32;    // 73728  w0 elems
  constexpr int J3 = 256 * 9 * 64;    // 147456 w1 elems
  const bf16x4 z4 = {};
  for (int u = (bid - 2048) * 256 + threadIdx.x; u < J0 + J1 + J2 + J3;
       u += NT) {
    if (u < J0) {
      const int n = u / 1056;        // 132*8
      const int rem = u - n * 1056;
      const int k = rem >> 3, c4 = rem & 7;
      int r, w;
      if (k < 68) { r = (k < 34) ? 0 : 33; w = k % 34; }
      else { const int e = k - 68; r = 1 + (e & 31); w = (e < 32) ? 0 : 33; }
      *reinterpret_cast<bf16x4*>(
          xT + ((size_t)(n * HP + r) * HP + w) * 32 + c4 * 4) = z4;
    } else if (u < J0 + J1) {
      const int v = u - J0;
      const int n = v / 2112;        // 132*16
      const int rem = v - n * 2112;
      const int k = rem >> 4, c4 = rem & 15;
      int r, w;
      if (k < 68) { r = (k < 34) ? 0 : 33; w = k % 34; }
      else { const int e = k - 68; r = 1 + (e & 31); w = (e < 32) ? 0 : 33; }
      *reinterpret_cast<bf16x4*>(
          h0T + ((size_t)(n * HP + r) * HP + w) * 64 + c4 * 4) = z4;
    } else if (u < J0 + J1 + J2) {
      const int g = u - (J0 + J1);
      const int j = g & 7;
      const int co = (g >> 3) & 255;
      const int r2 = g >> 11;
      const int ca = r2 & 3;         // CHUNKS=4
      const int t = r2 >> 2;
      const int ci = ca * 8 + j;
      w0T3[g] = (__bf16)w0[(size_t)(co * 32 + ci) * 9 + t];
    } else {
      const int g = u - (J0 + J1 + J2);
      const int j = g & 7;
      const int co = (g >> 3) & 255;
      const int r2 = g >> 11;
      const int ca = r2 & 7;         // CHUNKS=8
      const int t = r2 >> 3;
      const int ci = ca * 8 + j;
      w1T3[g] = (__bf16)w1[(size_t)(co * 64 + ci) * 9 + t];
    }
  }
}

// ---------------------------------------------------------------------------
// conv_gemm: implicit-GEMM 3x3 conv, bf16 MFMA 16x16x32. (R12, unchanged)
// lsA: chunk-major [CHUNKS][6*34] bf16x8 — staged ONCE; all 9 taps read at
//      tap-constant offsets. ONE barrier total. Weights global->VGPR,
//      [t%3] triple buffer, 2 taps ahead, compiler-tracked vmcnt.
// ---------------------------------------------------------------------------
template <int CIN, bool LAYER1>
__global__ __launch_bounds__(256, 2) void conv_gemm_k(
    const __bf16* __restrict__ xT,   // padded NHWC (64,34,34,CIN)
    const __bf16* __restrict__ wT3,  // [9][CHUNKS][256][8]
    const float* __restrict__ bias,  // [256]
    __bf16* __restrict__ gates) {
  constexpr int NKK = CIN / 32;
  constexpr int CHUNKS = CIN / 8;
  constexpr int PLANE = 204;        // 6*34
  __shared__ bf16x8 lsA[CHUNKS * PLANE];

  const int tid = threadIdx.x;
  const int lane = tid & 63;
  const int wid = tid >> 6;
  const int wr = wid >> 1, wc = wid & 1;
  const int g = lane >> 4;
  const int li = lane & 15;

  const int bx = blockIdx.x;
  const int by = blockIdx.y;
  const int n = bx >> 3;
  const int h0 = (bx & 7) << 2;
  const int co0 = by << 7;

  f32x4 acc[4][4] = {};

  for (int gi = tid; gi < CHUNKS * PLANE; gi += 256) {
    const int ch = gi & (CHUNKS - 1);
    const int pos = gi / CHUNKS;
    const int r = pos / 34;
    const int w = pos - r * 34;
    lsA[ch * PLANE + pos] = *reinterpret_cast<const bf16x8*>(
        xT + ((size_t)(n * HP + h0 + r) * HP + w) * CIN + ch * 8);
  }

  int posm[4];
#pragma unroll
  for (int mi = 0; mi < 4; ++mi) {
    const int m = wr * 64 + mi * 16 + li;
    posm[mi] = (m >> 5) * 34 + (m & 31);
  }

  const bf16x8* wp = reinterpret_cast<const bf16x8*>(wT3);
  const int cobase = co0 + wc * 64 + li;

  bf16x8 wreg[3][NKK][4];
  auto loadW = [&](int buf, int t) {
#pragma unroll
    for (int kk = 0; kk < NKK; ++kk)
#pragma unroll
      for (int ni = 0; ni < 4; ++ni)
        wreg[buf][kk][ni] =
            wp[(size_t)(t * CHUNKS + kk * 4 + g) * 256 + cobase + ni * 16];
  };

  loadW(0, 0);
  loadW(1, 1);
  __syncthreads();

#pragma unroll
  for (int t = 0; t < 9; ++t) {
    if (t < 7) loadW((t + 2) % 3, t + 2);
    const int kh = t / 3;
    const int kw = t - kh * 3;
    const int tapoff = kh * 34 + kw;
    const int buf = t % 3;
#pragma unroll
    for (int kk = 0; kk < NKK; ++kk) {
      const int ca = kk * 4 + g;
      bf16x8 af[4];
#pragma unroll
      for (int mi = 0; mi < 4; ++mi)
        af[mi] = lsA[ca * PLANE + posm[mi] + tapoff];
#pragma unroll
      for (int mi = 0; mi < 4; ++mi)
#pragma unroll
        for (int ni = 0; ni < 4; ++ni) {
          if constexpr (!LAYER1)
            acc[mi][ni] = __builtin_amdgcn_mfma_f32_16x16x32_bf16(
                af[mi], wreg[buf][kk][ni], acc[mi][ni], 0, 0, 0);
          else
            acc[mi][ni] = __builtin_amdgcn_mfma_f32_16x16x32_bf16(
                wreg[buf][kk][ni], af[mi], acc[mi][ni], 0, 0, 0);
        }
    }
  }

  // epilogue: C/D map col=lane&15, row=(lane>>4)*4+r
#pragma unroll
  for (int mi = 0; mi < 4; ++mi)
#pragma unroll
    for (int ni = 0; ni < 4; ++ni)
#pragma unroll
      for (int r = 0; r < 4; ++r) {
        if constexpr (!LAYER1) {
          const int m_loc = wr * 64 + mi * 16 + (g << 2) + r;
          const int co = co0 + wc * 64 + ni * 16 + li;
          const size_t m = (size_t)bx * 128 + m_loc;
          gates[m * 256 + co] = (__bf16)(acc[mi][ni][r] + bias[co]);
        } else {
          const int co = co0 + wc * 64 + ni * 16 + (g << 2) + r;
          const int m_loc = wr * 64 + mi * 16 + li;
          const int m = bx * 128 + m_loc;
          const int nimg = m >> 10, p = m & 1023;
          gates[((size_t)nimg * 256 + co) * 1024 + p] =
              (__bf16)(acc[mi][ni][r] + bias[co]);
        }
      }
}

// ---------------------------------------------------------------------------
// scan0: gates [m][256] bf16 -> h0T padded NHWC bf16 (64,34,34,64)
// ---------------------------------------------------------------------------
__global__ __launch_bounds__(256) void scan0_k(const __bf16* __restrict__ gates,
                                               __bf16* __restrict__ h0T) {
  const int g = blockIdx.x * 256 + threadIdx.x;  // 4*1024*16
  const int c = (g & 15) * 4;
  const int p = (g >> 4) & 1023;
  const int b = g >> 14;
  const int h = p >> 5, w = p & 31;
  float cst[4] = {0.5f, 0.5f, 0.5f, 0.5f};
#pragma unroll 4
  for (int s = 0; s < 16; ++s) {
    const size_t base = ((size_t)((b * 16 + s) * 1024 + p)) * 256 + c;
    const bf16x4* gp = reinterpret_cast<const bf16x4*>(gates + base);
    const bf16x4 ig4 = gp[0], fg4 = gp[16], og4 = gp[32], cd4 = gp[48];
    bf16x4 hv4;
#pragma unroll
    for (int j = 0; j < 4; ++j) {
      const float it = sigf((float)ig4[j]), ft = sigf((float)fg4[j]);
      const float inv = 1.0f / (it + ft);
      const float cd_ = (float)cd4[j];
      const float gc = (cd_ >= 0.0f) ? (cd_ + 0.5f) : sigf(cd_);
      cst[j] = (ft * inv) * cst[j] + (it * inv) * gc;
      hv4[j] = (__bf16)(sigf((float)og4[j]) * cst[j]);
    }
    *reinterpret_cast<bf16x4*>(
        h0T + ((size_t)((b * 16 + s) * HP + h + 1) * HP + (w + 1)) * 64 + c) = hv4;
  }
}

// ---------------------------------------------------------------------------
// scan1: gates [n][256][1024] bf16 -> out fp32 (B,S,64,32,32)
// ---------------------------------------------------------------------------
__global__ __launch_bounds__(256) void scan1_k(const __bf16* __restrict__ gates,
                                               float* __restrict__ out) {
  const int g = blockIdx.x * 256 + threadIdx.x;  // 4*64*256
  const int p0 = (g & 255) * 4;
  const int c = (g >> 8) & 63;
  const int b = g >> 14;
  float cst[4] = {0.5f, 0.5f, 0.5f, 0.5f};
#pragma unroll 2
  for (int s = 0; s < 16; ++s) {
    const size_t base = ((size_t)(b * 16 + s) * 256 + c) * 1024 + p0;
    const bf16x4 ig4 = *reinterpret_cast<const bf16x4*>(gates + base);
    const bf16x4 fg4 = *reinterpret_cast<const bf16x4*>(gates + base + 64 * 1024);
    const bf16x4 og4 = *reinterpret_cast<const bf16x4*>(gates + base + 128 * 1024);
    const bf16x4 cd4 = *reinterpret_cast<const bf16x4*>(gates + base + 192 * 1024);
    f32x4 hv;
#pragma unroll
    for (int j = 0; j < 4; ++j) {
      const float it = sigf((float)ig4[j]), ft = sigf((float)fg4[j]);
      const float inv = 1.0f / (it + ft);
      const float cd_ = (float)cd4[j];
      const float gc = (cd_ >= 0.0f) ? (cd_ + 0.5f) : sigf(cd_);
      cst[j] = (ft * inv) * cst[j] + (it * inv) * gc;
      hv[j] = sigf((float)og4[j]) * cst[j];
    }
    *reinterpret_cast<f32x4*>(
        out + ((size_t)((b * 16 + s) * 64 + c)) * 1024 + p0) = hv;
  }
}

// ---------------------------------------------------------------------------
extern "C" void kernel_launch(void* const* d_in, const int* in_sizes, int n_in,
                              void* d_out, int out_size, void* d_ws,
                              size_t ws_size, hipStream_t stream) {
  const float* x = (const float*)d_in[0];   // (4,16,32,32,32)
  const float* w0 = (const float*)d_in[1];  // (256,32,3,3)
  const float* b0 = (const float*)d_in[2];  // (256)
  const float* w1 = (const float*)d_in[3];  // (256,64,3,3)
  const float* b1 = (const float*)d_in[4];  // (256)
  float* out = (float*)d_out;               // (4,16,64,32,32)

  char* ws = (char*)d_ws;
  const size_t XT_BYTES = (size_t)N_IMG * HP * HP * 32 * 2;
  const size_t H0_BYTES = (size_t)N_IMG * HP * HP * 64 * 2;
  const size_t W0T_BYTES = (size_t)256 * 9 * 32 * 2;
  const size_t W1T_BYTES = (size_t)256 * 9 * 64 * 2;
  __bf16* xT = (__bf16*)ws;
  __bf16* h0T = (__bf16*)(ws + XT_BYTES);
  __bf16* w0T = (__bf16*)(ws + XT_BYTES + H0_BYTES);
  __bf16* w1T = (__bf16*)(ws + XT_BYTES + H0_BYTES + W0T_BYTES);
  __bf16* gates = (__bf16*)(ws + XT_BYTES + H0_BYTES + W0T_BYTES + W1T_BYTES);
  (void)ws_size; (void)n_in; (void)in_sizes; (void)out_size;

  // 5 graph nodes total (was 9): prep, conv0, scan0, conv1, scan1
  prep_k<<<2560, 256, 0, stream>>>(x, w0, w1, xT, h0T, w0T, w1T);
  conv_gemm_k<32, false><<<dim3(512, 2), 256, 0, stream>>>(xT, w0T, b0, gates);
  scan0_k<<<256, 256, 0, stream>>>(gates, h0T);
  conv_gemm_k<64, true><<<dim3(512, 2), 256, 0, stream>>>(h0T, w1T, b1, gates);
  scan1_k<<<256, 256, 0, stream>>>(gates, out);
}

// Round 16
// 152.046 us; speedup vs baseline: 1.0849x; 1.0371x over previous
//
#include <hip/hip_runtime.h>

// ---------------------------------------------------------------------------
// MinConv2dLSTM: 2x (3x3 conv -> minLSTM gates -> scan over S)
// B=4 S=16 H=W=32, layer0: Cin=32, layer1: Cin=64, gates Cout=256 (4x64)
// R16: LDS-transpose conv epilogue. Replaces 64 scalar 2B stores/thread
//      (32B-segment L2 scatter) with lsC[128][136] staging + 8 dense
//      global_store_dwordx4/thread. Main loop/prep/scans identical to R15.
// ---------------------------------------------------------------------------

typedef __bf16 bf16x8 __attribute__((ext_vector_type(8)));
typedef __bf16 bf16x4 __attribute__((ext_vector_type(4)));
typedef float f32x4 __attribute__((ext_vector_type(4)));

#define N_IMG 64      // B*S
#define HP 34         // padded H/W
#define COUT 256

__device__ __forceinline__ float sigf(float x) { return 1.0f / (1.0f + __expf(-x)); }

// ---------------------------------------------------------------------------
// prep_k: ONE kernel for all preprocessing. (identical to R15)
// ---------------------------------------------------------------------------
__global__ __launch_bounds__(256) void prep_k(
    const float* __restrict__ x, const float* __restrict__ w0,
    const float* __restrict__ w1, __bf16* __restrict__ xT,
    __bf16* __restrict__ h0T, __bf16* __restrict__ w0T3,
    __bf16* __restrict__ w1T3) {
  const int bid = blockIdx.x;
  if (bid < 2048) {
    __shared__ float ls[32][33];
    const int n = bid >> 5;
    const int h = bid & 31;
    const int t = threadIdx.x;
    {
      const int w = t & 31, g4 = t >> 5;
      const float* src = x + (((size_t)n * 32) << 10) + (h << 5);
#pragma unroll
      for (int j = 0; j < 4; ++j) {
        int ci = g4 * 4 + j;
        ls[ci][w] = src[((size_t)ci << 10) + w];
      }
    }
    __syncthreads();
    {
      const int ci = t & 31, w4 = t >> 5;
      __bf16* dst = xT + ((size_t)(n * HP + h + 1) * HP + 1) * 32 + ci;
#pragma unroll
      for (int j = 0; j < 4; ++j) {
        int w = w4 * 4 + j;
        dst[w * 32] = (__bf16)ls[ci][w];
      }
    }
    return;
  }
  constexpr int NT = 512 * 256;
  constexpr int J0 = 64 * 132 * 8;
  constexpr int J1 = 64 * 132 * 16;
  constexpr int J2 = 256 * 9 * 32;
  constexpr int J3 = 256 * 9 * 64;
  const bf16x4 z4 = {};
  for (int u = (bid - 2048) * 256 + threadIdx.x; u < J0 + J1 + J2 + J3;
       u += NT) {
    if (u < J0) {
      const int n = u / 1056;
      const int rem = u - n * 1056;
      const int k = rem >> 3, c4 = rem & 7;
      int r, w;
      if (k < 68) { r = (k < 34) ? 0 : 33; w = k % 34; }
      else { const int e = k - 68; r = 1 + (e & 31); w = (e < 32) ? 0 : 33; }
      *reinterpret_cast<bf16x4*>(
          xT + ((size_t)(n * HP + r) * HP + w) * 32 + c4 * 4) = z4;
    } else if (u < J0 + J1) {
      const int v = u - J0;
      const int n = v / 2112;
      const int rem = v - n * 2112;
      const int k = rem >> 4, c4 = rem & 15;
      int r, w;
      if (k < 68) { r = (k < 34) ? 0 : 33; w = k % 34; }
      else { const int e = k - 68; r = 1 + (e & 31); w = (e < 32) ? 0 : 33; }
      *reinterpret_cast<bf16x4*>(
          h0T + ((size_t)(n * HP + r) * HP + w) * 64 + c4 * 4) = z4;
    } else if (u < J0 + J1 + J2) {
      const int g = u - (J0 + J1);
      const int j = g & 7;
      const int co = (g >> 3) & 255;
      const int r2 = g >> 11;
      const int ca = r2 & 3;
      const int t = r2 >> 2;
      const int ci = ca * 8 + j;
      w0T3[g] = (__bf16)w0[(size_t)(co * 32 + ci) * 9 + t];
    } else {
      const int g = u - (J0 + J1 + J2);
      const int j = g & 7;
      const int co = (g >> 3) & 255;
      const int r2 = g >> 11;
      const int ca = r2 & 7;
      const int t = r2 >> 3;
      const int ci = ca * 8 + j;
      w1T3[g] = (__bf16)w1[(size_t)(co * 64 + ci) * 9 + t];
    }
  }
}

// ---------------------------------------------------------------------------
// conv_gemm: implicit-GEMM 3x3 conv, bf16 MFMA 16x16x32.
// Main loop identical to R15 (A-resident LDS, weights global->VGPR 3-buf).
// NEW epilogue: acc -> lsC[128][136] bf16 (union with lsA) -> dense
// bf16x8 global stores (256B-contiguous per row chunk).
// ---------------------------------------------------------------------------
template <int CIN, bool LAYER1>
__global__ __launch_bounds__(256, 2) void conv_gemm_k(
    const __bf16* __restrict__ xT,   // padded NHWC (64,34,34,CIN)
    const __bf16* __restrict__ wT3,  // [9][CHUNKS][256][8]
    const float* __restrict__ bias,  // [256]
    __bf16* __restrict__ gates) {
  constexpr int NKK = CIN / 32;
  constexpr int CHUNKS = CIN / 8;
  constexpr int PLANE = 204;        // 6*34
  constexpr int LDC = 136;          // 128 + 8 pad
  constexpr size_t LSA_B = (size_t)CHUNKS * PLANE * 16;
  constexpr size_t LSC_B = (size_t)128 * LDC * 2;
  __shared__ char lsmem[LSA_B > LSC_B ? LSA_B : LSC_B];
  bf16x8* lsA = reinterpret_cast<bf16x8*>(lsmem);
  __bf16* lsC = reinterpret_cast<__bf16*>(lsmem);

  const int tid = threadIdx.x;
  const int lane = tid & 63;
  const int wid = tid >> 6;
  const int wr = wid >> 1, wc = wid & 1;
  const int g = lane >> 4;
  const int li = lane & 15;

  const int bx = blockIdx.x;
  const int by = blockIdx.y;
  const int n = bx >> 3;
  const int h0 = (bx & 7) << 2;
  const int co0 = by << 7;

  f32x4 acc[4][4] = {};

  for (int gi = tid; gi < CHUNKS * PLANE; gi += 256) {
    const int ch = gi & (CHUNKS - 1);
    const int pos = gi / CHUNKS;
    const int r = pos / 34;
    const int w = pos - r * 34;
    lsA[ch * PLANE + pos] = *reinterpret_cast<const bf16x8*>(
        xT + ((size_t)(n * HP + h0 + r) * HP + w) * CIN + ch * 8);
  }

  int posm[4];
#pragma unroll
  for (int mi = 0; mi < 4; ++mi) {
    const int m = wr * 64 + mi * 16 + li;
    posm[mi] = (m >> 5) * 34 + (m & 31);
  }

  const bf16x8* wp = reinterpret_cast<const bf16x8*>(wT3);
  const int cobase = co0 + wc * 64 + li;

  bf16x8 wreg[3][NKK][4];
  auto loadW = [&](int buf, int t) {
#pragma unroll
    for (int kk = 0; kk < NKK; ++kk)
#pragma unroll
      for (int ni = 0; ni < 4; ++ni)
        wreg[buf][kk][ni] =
            wp[(size_t)(t * CHUNKS + kk * 4 + g) * 256 + cobase + ni * 16];
  };

  loadW(0, 0);
  loadW(1, 1);
  __syncthreads();

#pragma unroll
  for (int t = 0; t < 9; ++t) {
    if (t < 7) loadW((t + 2) % 3, t + 2);
    const int kh = t / 3;
    const int kw = t - kh * 3;
    const int tapoff = kh * 34 + kw;
    const int buf = t % 3;
#pragma unroll
    for (int kk = 0; kk < NKK; ++kk) {
      const int ca = kk * 4 + g;
      bf16x8 af[4];
#pragma unroll
      for (int mi = 0; mi < 4; ++mi)
        af[mi] = lsA[ca * PLANE + posm[mi] + tapoff];
#pragma unroll
      for (int mi = 0; mi < 4; ++mi)
#pragma unroll
        for (int ni = 0; ni < 4; ++ni) {
          if constexpr (!LAYER1)
            acc[mi][ni] = __builtin_amdgcn_mfma_f32_16x16x32_bf16(
                af[mi], wreg[buf][kk][ni], acc[mi][ni], 0, 0, 0);
          else
            acc[mi][ni] = __builtin_amdgcn_mfma_f32_16x16x32_bf16(
                wreg[buf][kk][ni], af[mi], acc[mi][ni], 0, 0, 0);
        }
    }
  }

  // ---- epilogue: LDS transpose + dense stores ----
  __syncthreads();          // all lsA reads complete; reuse as lsC
  // write phase (C/D map col=lane&15, row=(lane>>4)*4+r):
  //  !LAYER1: D row = m_loc, D col = co_loc -> lsC[m][co]
  //   LAYER1: operands swapped -> D row = co_loc, D col = m_loc -> lsC[co][m]
#pragma unroll
  for (int mi = 0; mi < 4; ++mi)
#pragma unroll
    for (int ni = 0; ni < 4; ++ni)
#pragma unroll
      for (int r = 0; r < 4; ++r) {
        if constexpr (!LAYER1) {
          const int row = wr * 64 + mi * 16 + (g << 2) + r;   // m_loc
          const int col = wc * 64 + ni * 16 + li;             // co_loc
          lsC[row * LDC + col] = (__bf16)(acc[mi][ni][r] + bias[co0 + col]);
        } else {
          const int row = wc * 64 + ni * 16 + (g << 2) + r;   // co_loc
          const int col = wr * 64 + mi * 16 + li;             // m_loc
          lsC[row * LDC + col] = (__bf16)(acc[mi][ni][r] + bias[co0 + row]);
        }
      }
  __syncthreads();
  // read+store phase: 16 lanes x 16B cover one 128-col row (256B dense)
  {
    const int j = tid & 15;        // 16B chunk within row
    const int r0 = tid >> 4;       // 16 row groups
#pragma unroll
    for (int it = 0; it < 8; ++it) {
      const int row = r0 + it * 16;
      const bf16x8 v =
          *reinterpret_cast<const bf16x8*>(&lsC[row * LDC + j * 8]);
      if constexpr (!LAYER1) {
        const size_t m = (size_t)bx * 128 + row;
        *reinterpret_cast<bf16x8*>(&gates[m * 256 + co0 + j * 8]) = v;
      } else {
        const int m0 = bx * 128;
        const int nimg = m0 >> 10, p0 = m0 & 1023;
        *reinterpret_cast<bf16x8*>(
            &gates[((size_t)nimg * 256 + co0 + row) * 1024 + p0 + j * 8]) = v;
      }
    }
  }
}

// ---------------------------------------------------------------------------
// scan0: gates [m][256] bf16 -> h0T padded NHWC bf16 (64,34,34,64)
// ---------------------------------------------------------------------------
__global__ __launch_bounds__(256) void scan0_k(const __bf16* __restrict__ gates,
                                               __bf16* __restrict__ h0T) {
  const int g = blockIdx.x * 256 + threadIdx.x;  // 4*1024*16
  const int c = (g & 15) * 4;
  const int p = (g >> 4) & 1023;
  const int b = g >> 14;
  const int h = p >> 5, w = p & 31;
  float cst[4] = {0.5f, 0.5f, 0.5f, 0.5f};
#pragma unroll 4
  for (int s = 0; s < 16; ++s) {
    const size_t base = ((size_t)((b * 16 + s) * 1024 + p)) * 256 + c;
    const bf16x4* gp = reinterpret_cast<const bf16x4*>(gates + base);
    const bf16x4 ig4 = gp[0], fg4 = gp[16], og4 = gp[32], cd4 = gp[48];
    bf16x4 hv4;
#pragma unroll
    for (int j = 0; j < 4; ++j) {
      const float it = sigf((float)ig4[j]), ft = sigf((float)fg4[j]);
      const float inv = 1.0f / (it + ft);
      const float cd_ = (float)cd4[j];
      const float gc = (cd_ >= 0.0f) ? (cd_ + 0.5f) : sigf(cd_);
      cst[j] = (ft * inv) * cst[j] + (it * inv) * gc;
      hv4[j] = (__bf16)(sigf((float)og4[j]) * cst[j]);
    }
    *reinterpret_cast<bf16x4*>(
        h0T + ((size_t)((b * 16 + s) * HP + h + 1) * HP + (w + 1)) * 64 + c) = hv4;
  }
}

// ---------------------------------------------------------------------------
// scan1: gates [n][256][1024] bf16 -> out fp32 (B,S,64,32,32)
// ---------------------------------------------------------------------------
__global__ __launch_bounds__(256) void scan1_k(const __bf16* __restrict__ gates,
                                               float* __restrict__ out) {
  const int g = blockIdx.x * 256 + threadIdx.x;  // 4*64*256
  const int p0 = (g & 255) * 4;
  const int c = (g >> 8) & 63;
  const int b = g >> 14;
  float cst[4] = {0.5f, 0.5f, 0.5f, 0.5f};
#pragma unroll 2
  for (int s = 0; s < 16; ++s) {
    const size_t base = ((size_t)(b * 16 + s) * 256 + c) * 1024 + p0;
    const bf16x4 ig4 = *reinterpret_cast<const bf16x4*>(gates + base);
    const bf16x4 fg4 = *reinterpret_cast<const bf16x4*>(gates + base + 64 * 1024);
    const bf16x4 og4 = *reinterpret_cast<const bf16x4*>(gates + base + 128 * 1024);
    const bf16x4 cd4 = *reinterpret_cast<const bf16x4*>(gates + base + 192 * 1024);
    f32x4 hv;
#pragma unroll
    for (int j = 0; j < 4; ++j) {
      const float it = sigf((float)ig4[j]), ft = sigf((float)fg4[j]);
      const float inv = 1.0f / (it + ft);
      const float cd_ = (float)cd4[j];
      const float gc = (cd_ >= 0.0f) ? (cd_ + 0.5f) : sigf(cd_);
      cst[j] = (ft * inv) * cst[j] + (it * inv) * gc;
      hv[j] = sigf((float)og4[j]) * cst[j];
    }
    *reinterpret_cast<f32x4*>(
        out + ((size_t)((b * 16 + s) * 64 + c)) * 1024 + p0) = hv;
  }
}

// ---------------------------------------------------------------------------
extern "C" void kernel_launch(void* const* d_in, const int* in_sizes, int n_in,
                              void* d_out, int out_size, void* d_ws,
                              size_t ws_size, hipStream_t stream) {
  const float* x = (const float*)d_in[0];   // (4,16,32,32,32)
  const float* w0 = (const float*)d_in[1];  // (256,32,3,3)
  const float* b0 = (const float*)d_in[2];  // (256)
  const float* w1 = (const float*)d_in[3];  // (256,64,3,3)
  const float* b1 = (const float*)d_in[4];  // (256)
  float* out = (float*)d_out;               // (4,16,64,32,32)

  char* ws = (char*)d_ws;
  const size_t XT_BYTES = (size_t)N_IMG * HP * HP * 32 * 2;
  const size_t H0_BYTES = (size_t)N_IMG * HP * HP * 64 * 2;
  const size_t W0T_BYTES = (size_t)256 * 9 * 32 * 2;
  const size_t W1T_BYTES = (size_t)256 * 9 * 64 * 2;
  __bf16* xT = (__bf16*)ws;
  __bf16* h0T = (__bf16*)(ws + XT_BYTES);
  __bf16* w0T = (__bf16*)(ws + XT_BYTES + H0_BYTES);
  __bf16* w1T = (__bf16*)(ws + XT_BYTES + H0_BYTES + W0T_BYTES);
  __bf16* gates = (__bf16*)(ws + XT_BYTES + H0_BYTES + W0T_BYTES + W1T_BYTES);
  (void)ws_size; (void)n_in; (void)in_sizes; (void)out_size;

  // 5 graph nodes: prep, conv0, scan0, conv1, scan1
  prep_k<<<2560, 256, 0, stream>>>(x, w0, w1, xT, h0T, w0T, w1T);
  conv_gemm_k<32, false><<<dim3(512, 2), 256, 0, stream>>>(xT, w0T, b0, gates);
  scan0_k<<<256, 256, 0, stream>>>(gates, h0T);
  conv_gemm_k<64, true><<<dim3(512, 2), 256, 0, stream>>>(h0T, w1T, b1, gates);
  scan1_k<<<256, 256, 0, stream>>>(gates, out);
}